// Round 1
// baseline (980.507 us; speedup 1.0000x reference)
//
#include <hip/hip_runtime.h>
#include <math.h>

#define DIM 64

// ---------------------------------------------------------------------------
// Kernel A: per-node scores  s_src[i] = feat[i]·a[0:64], s_dst[i] = feat[i]·a[64:128]
// 16 lanes per node, float4 loads (fully coalesced 256B per node), shfl reduce.
// ---------------------------------------------------------------------------
__global__ void compute_scores(const float* __restrict__ feat,
                               const float* __restrict__ attn_w,
                               float* __restrict__ s_src,
                               float* __restrict__ s_dst,
                               int n_nodes) {
    int gid  = blockIdx.x * blockDim.x + threadIdx.x;
    int node = gid >> 4;
    int lane = gid & 15;
    if (node >= n_nodes) return;
    const float4 f  = *reinterpret_cast<const float4*>(feat + (size_t)node * DIM + lane * 4);
    const float4 as = *reinterpret_cast<const float4*>(attn_w + lane * 4);
    const float4 ad = *reinterpret_cast<const float4*>(attn_w + DIM + lane * 4);
    float ps = f.x * as.x + f.y * as.y + f.z * as.z + f.w * as.w;
    float pd = f.x * ad.x + f.y * ad.y + f.z * ad.z + f.w * ad.w;
    // reduce across the 16-lane group
    for (int off = 8; off >= 1; off >>= 1) {
        ps += __shfl_xor(ps, off, 16);
        pd += __shfl_xor(pd, off, 16);
    }
    if (lane == 0) {
        s_src[node] = ps;
        s_dst[node] = pd;
    }
}

__device__ __forceinline__ float edge_weight(float ss, float sd) {
    float e = ss + sd;
    e = (e > 0.f) ? e : 0.01f * e;          // leaky_relu(0.01)
    return __expf(e);                        // no max-subtraction needed: e <= ~6
}

// ---------------------------------------------------------------------------
// Kernel B: denom[d] = sum over edges with dst==d of exp(leaky_relu(s_src+s_dst))
// ---------------------------------------------------------------------------
__global__ void edge_denom(const int* __restrict__ src,
                           const int* __restrict__ dst,
                           const float* __restrict__ s_src,
                           const float* __restrict__ s_dst,
                           float* __restrict__ denom,
                           int n_edges) {
    int i = blockIdx.x * blockDim.x + threadIdx.x;
    if (i >= n_edges) return;
    int s = src[i], d = dst[i];
    atomicAdd(&denom[d], edge_weight(s_src[s], s_dst[d]));
}

// ---------------------------------------------------------------------------
// Kernel C: one wave per edge. lane l accumulates alpha * feat[src][l] into out[dst][l].
// Gather of feat row and atomic scatter to out row are both 256B contiguous per wave.
// ---------------------------------------------------------------------------
__global__ void edge_aggregate(const int* __restrict__ src,
                               const int* __restrict__ dst,
                               const float* __restrict__ s_src,
                               const float* __restrict__ s_dst,
                               const float* __restrict__ denom,
                               const float* __restrict__ feat,
                               float* __restrict__ out,
                               int n_edges) {
    int wave = blockIdx.x * (blockDim.x >> 6) + (threadIdx.x >> 6);
    int lane = threadIdx.x & 63;
    if (wave >= n_edges) return;
    int s = src[wave], d = dst[wave];
    float alpha = edge_weight(s_src[s], s_dst[d]) / denom[d];
    float v = alpha * feat[(size_t)s * DIM + lane];
    atomicAdd(&out[(size_t)d * DIM + lane], v);
}

// ---------------------------------------------------------------------------
// Kernel D: in-place ELU
// ---------------------------------------------------------------------------
__global__ void elu_kernel(float* __restrict__ out, int n) {
    int i = blockIdx.x * blockDim.x + threadIdx.x;
    if (i >= n) return;
    float x = out[i];
    out[i] = (x > 0.f) ? x : expm1f(x);
}

extern "C" void kernel_launch(void* const* d_in, const int* in_sizes, int n_in,
                              void* d_out, int out_size, void* d_ws, size_t ws_size,
                              hipStream_t stream) {
    const float* feat   = (const float*)d_in[0];
    const float* attn_w = (const float*)d_in[1];
    const int*   src    = (const int*)d_in[2];
    const int*   dst    = (const int*)d_in[3];

    const int n_nodes = in_sizes[0] / DIM;
    const int n_edges = in_sizes[2];

    float* out   = (float*)d_out;
    float* s_src = (float*)d_ws;           // n_nodes floats
    float* s_dst = s_src + n_nodes;        // n_nodes floats
    float* denom = s_dst + n_nodes;        // n_nodes floats

    // ws/out are poisoned 0xAA before every launch -> zero what we accumulate into.
    hipMemsetAsync(out,   0, (size_t)n_nodes * DIM * sizeof(float), stream);
    hipMemsetAsync(denom, 0, (size_t)n_nodes * sizeof(float), stream);

    {   // A: scores
        int threads = n_nodes * 16;
        compute_scores<<<(threads + 255) / 256, 256, 0, stream>>>(
            feat, attn_w, s_src, s_dst, n_nodes);
    }
    {   // B: softmax denominators
        edge_denom<<<(n_edges + 255) / 256, 256, 0, stream>>>(
            src, dst, s_src, s_dst, denom, n_edges);
    }
    {   // C: weighted aggregation, 1 wave per edge, 4 waves per block
        int blocks = (n_edges + 3) / 4;
        edge_aggregate<<<blocks, 256, 0, stream>>>(
            src, dst, s_src, s_dst, denom, feat, out, n_edges);
    }
    {   // D: ELU epilogue
        int n = n_nodes * DIM;
        elu_kernel<<<(n + 255) / 256, 256, 0, stream>>>(out, n);
    }
}

// Round 2
// 396.425 us; speedup vs baseline: 2.4734x; 2.4734x over previous
//
#include <hip/hip_runtime.h>
#include <math.h>

#define DIM 64
#define SCAN_BLOCK 1024

// ---------------------------------------------------------------------------
// Kernel A: per-node scores  s_src[i] = feat[i]·a[0:64], s_dst[i] = feat[i]·a[64:128]
// ---------------------------------------------------------------------------
__global__ void compute_scores(const float* __restrict__ feat,
                               const float* __restrict__ attn_w,
                               float* __restrict__ s_src,
                               float* __restrict__ s_dst,
                               int n_nodes) {
    int gid  = blockIdx.x * blockDim.x + threadIdx.x;
    int node = gid >> 4;
    int lane = gid & 15;
    if (node >= n_nodes) return;
    const float4 f  = *reinterpret_cast<const float4*>(feat + (size_t)node * DIM + lane * 4);
    const float4 as = *reinterpret_cast<const float4*>(attn_w + lane * 4);
    const float4 ad = *reinterpret_cast<const float4*>(attn_w + DIM + lane * 4);
    float ps = f.x * as.x + f.y * as.y + f.z * as.z + f.w * as.w;
    float pd = f.x * ad.x + f.y * ad.y + f.z * ad.z + f.w * ad.w;
    for (int off = 8; off >= 1; off >>= 1) {
        ps += __shfl_xor(ps, off, 16);
        pd += __shfl_xor(pd, off, 16);
    }
    if (lane == 0) {
        s_src[node] = ps;
        s_dst[node] = pd;
    }
}

// ---------------------------------------------------------------------------
// CSR build, step 1: deg[d]++ and remember each edge's rank within its segment
// (so the scatter needs no second atomic pass).
// ---------------------------------------------------------------------------
__global__ void degree_rank(const int* __restrict__ dst,
                            int* __restrict__ deg,
                            int* __restrict__ rank,
                            int m) {
    int i = blockIdx.x * blockDim.x + threadIdx.x;
    if (i >= m) return;
    rank[i] = atomicAdd(&deg[dst[i]], 1);
}

// ---------------------------------------------------------------------------
// CSR build, step 2: two-level exclusive scan of deg -> offs
// ---------------------------------------------------------------------------
__global__ void scan_level1(const int* __restrict__ deg,
                            int* __restrict__ offs,
                            int* __restrict__ bsum,
                            int n) {
    __shared__ int tmp[SCAN_BLOCK];
    int t = threadIdx.x;
    int g = blockIdx.x * SCAN_BLOCK + t;
    int v = (g < n) ? deg[g] : 0;
    tmp[t] = v;
    __syncthreads();
    for (int off = 1; off < SCAN_BLOCK; off <<= 1) {
        int u = (t >= off) ? tmp[t - off] : 0;
        __syncthreads();
        tmp[t] += u;
        __syncthreads();
    }
    if (g < n) offs[g] = tmp[t] - v;              // exclusive
    if (t == SCAN_BLOCK - 1) bsum[blockIdx.x] = tmp[t];
}

__global__ void scan_level2(int* __restrict__ bsum, int nb) {
    __shared__ int tmp[SCAN_BLOCK];
    int t = threadIdx.x;
    int v = (t < nb) ? bsum[t] : 0;
    tmp[t] = v;
    __syncthreads();
    for (int off = 1; off < SCAN_BLOCK; off <<= 1) {
        int u = (t >= off) ? tmp[t - off] : 0;
        __syncthreads();
        tmp[t] += u;
        __syncthreads();
    }
    if (t < nb) bsum[t] = tmp[t] - v;             // exclusive
}

__global__ void scan_level3(int* __restrict__ offs,
                            const int* __restrict__ bsum,
                            int n) {
    int g = blockIdx.x * SCAN_BLOCK + threadIdx.x;
    if (g < n) offs[g] += bsum[blockIdx.x];
}

// ---------------------------------------------------------------------------
// CSR build, step 3: scatter src ids into dst-sorted order (no atomics).
// ---------------------------------------------------------------------------
__global__ void scatter_src(const int* __restrict__ src,
                            const int* __restrict__ dst,
                            const int* __restrict__ rank,
                            const int* __restrict__ offs,
                            int* __restrict__ esrc,
                            int m) {
    int i = blockIdx.x * blockDim.x + threadIdx.x;
    if (i >= m) return;
    int d = dst[i];
    esrc[offs[d] + rank[i]] = src[i];
}

// ---------------------------------------------------------------------------
// Fused denom + weighted aggregation + ELU. 16 lanes per node, each lane owns
// a float4 of the 64-dim row. wsum (= softmax denominator) is computed
// redundantly per lane; out = elu(acc / wsum). No atomics anywhere.
// ---------------------------------------------------------------------------
__device__ __forceinline__ float lrelu(float x) { return x > 0.f ? x : 0.01f * x; }
__device__ __forceinline__ float elu(float x)  { return x > 0.f ? x : expm1f(x); }

__global__ void aggregate(const int* __restrict__ esrc,
                          const int* __restrict__ offs,
                          const int* __restrict__ deg,
                          const float* __restrict__ s_src,
                          const float* __restrict__ s_dst,
                          const float* __restrict__ feat,
                          float* __restrict__ out,
                          int n) {
    int gid  = blockIdx.x * blockDim.x + threadIdx.x;
    int node = gid >> 4;
    int lane = gid & 15;
    if (node >= n) return;
    int start = offs[node];
    int cnt   = deg[node];
    float sdd = s_dst[node];
    const float4* fv = reinterpret_cast<const float4*>(feat);
    float4 acc = {0.f, 0.f, 0.f, 0.f};
    float wsum = 0.f;
    int e = 0;
    for (; e + 2 <= cnt; e += 2) {
        int s0 = esrc[start + e];
        int s1 = esrc[start + e + 1];
        float w0 = __expf(lrelu(s_src[s0] + sdd));
        float w1 = __expf(lrelu(s_src[s1] + sdd));
        float4 f0 = fv[s0 * 16 + lane];
        float4 f1 = fv[s1 * 16 + lane];
        wsum += w0 + w1;
        acc.x += w0 * f0.x + w1 * f1.x;
        acc.y += w0 * f0.y + w1 * f1.y;
        acc.z += w0 * f0.z + w1 * f1.z;
        acc.w += w0 * f0.w + w1 * f1.w;
    }
    if (e < cnt) {
        int s0 = esrc[start + e];
        float w0 = __expf(lrelu(s_src[s0] + sdd));
        float4 f0 = fv[s0 * 16 + lane];
        wsum += w0;
        acc.x += w0 * f0.x;
        acc.y += w0 * f0.y;
        acc.z += w0 * f0.z;
        acc.w += w0 * f0.w;
    }
    float inv = (cnt > 0) ? 1.f / wsum : 0.f;
    float4 o;
    o.x = elu(acc.x * inv);
    o.y = elu(acc.y * inv);
    o.z = elu(acc.z * inv);
    o.w = elu(acc.w * inv);
    reinterpret_cast<float4*>(out)[node * 16 + lane] = o;
}

// ---------------------------------------------------------------------------
// Fallback (round-1 atomic path) if ws_size is too small for CSR buffers.
// ---------------------------------------------------------------------------
__device__ __forceinline__ float edge_weight(float ss, float sd) {
    return __expf(lrelu(ss + sd));
}

__global__ void edge_denom(const int* __restrict__ src, const int* __restrict__ dst,
                           const float* __restrict__ s_src, const float* __restrict__ s_dst,
                           float* __restrict__ denom, int n_edges) {
    int i = blockIdx.x * blockDim.x + threadIdx.x;
    if (i >= n_edges) return;
    atomicAdd(&denom[dst[i]], edge_weight(s_src[src[i]], s_dst[dst[i]]));
}

__global__ void edge_aggregate(const int* __restrict__ src, const int* __restrict__ dst,
                               const float* __restrict__ s_src, const float* __restrict__ s_dst,
                               const float* __restrict__ denom, const float* __restrict__ feat,
                               float* __restrict__ out, int n_edges) {
    int wave = blockIdx.x * (blockDim.x >> 6) + (threadIdx.x >> 6);
    int lane = threadIdx.x & 63;
    if (wave >= n_edges) return;
    int s = src[wave], d = dst[wave];
    float alpha = edge_weight(s_src[s], s_dst[d]) / denom[d];
    atomicAdd(&out[(size_t)d * DIM + lane], alpha * feat[(size_t)s * DIM + lane]);
}

__global__ void elu_kernel(float* __restrict__ out, int n) {
    int i = blockIdx.x * blockDim.x + threadIdx.x;
    if (i >= n) return;
    float x = out[i];
    out[i] = (x > 0.f) ? x : expm1f(x);
}

extern "C" void kernel_launch(void* const* d_in, const int* in_sizes, int n_in,
                              void* d_out, int out_size, void* d_ws, size_t ws_size,
                              hipStream_t stream) {
    const float* feat   = (const float*)d_in[0];
    const float* attn_w = (const float*)d_in[1];
    const int*   src    = (const int*)d_in[2];
    const int*   dst    = (const int*)d_in[3];

    const int n = in_sizes[0] / DIM;   // n_nodes
    const int m = in_sizes[2];         // n_edges

    float* out = (float*)d_out;

    // ws layout
    float* s_src = (float*)d_ws;                  // n
    float* s_dst = s_src + n;                     // n
    int*   deg   = (int*)(s_dst + n);             // n
    int*   offs  = deg + n;                       // n
    int*   bsum  = offs + n;                      // SCAN_BLOCK
    int*   rank  = bsum + SCAN_BLOCK;             // m
    int*   esrc  = rank + m;                      // m
    size_t need  = ((size_t)4 * n + SCAN_BLOCK + 2 * (size_t)m) * sizeof(int);

    {   // A: scores (needed by both paths)
        int threads = n * 16;
        compute_scores<<<(threads + 255) / 256, 256, 0, stream>>>(
            feat, attn_w, s_src, s_dst, n);
    }

    if (ws_size >= need) {
        // --- CSR path: no float atomics anywhere ---
        hipMemsetAsync(deg, 0, (size_t)n * sizeof(int), stream);

        degree_rank<<<(m + 255) / 256, 256, 0, stream>>>(dst, deg, rank, m);

        int nb = (n + SCAN_BLOCK - 1) / SCAN_BLOCK;   // 98 for n=100000; must be <= SCAN_BLOCK
        scan_level1<<<nb, SCAN_BLOCK, 0, stream>>>(deg, offs, bsum, n);
        scan_level2<<<1, SCAN_BLOCK, 0, stream>>>(bsum, nb);
        scan_level3<<<nb, SCAN_BLOCK, 0, stream>>>(offs, bsum, n);

        scatter_src<<<(m + 255) / 256, 256, 0, stream>>>(src, dst, rank, offs, esrc, m);

        int threads = n * 16;
        aggregate<<<(threads + 255) / 256, 256, 0, stream>>>(
            esrc, offs, deg, s_src, s_dst, feat, out, n);
    } else {
        // --- fallback: round-1 atomic path ---
        float* denom = (float*)(s_dst + n);
        hipMemsetAsync(out,   0, (size_t)n * DIM * sizeof(float), stream);
        hipMemsetAsync(denom, 0, (size_t)n * sizeof(float), stream);
        edge_denom<<<(m + 255) / 256, 256, 0, stream>>>(src, dst, s_src, s_dst, denom, m);
        edge_aggregate<<<(m + 3) / 4, 256, 0, stream>>>(src, dst, s_src, s_dst, denom, feat, out, m);
        elu_kernel<<<(n * DIM + 255) / 256, 256, 0, stream>>>(out, n * DIM);
    }
}